// Round 6
// baseline (1021.865 us; speedup 1.0000x reference)
//
#include <hip/hip_runtime.h>
#include <hip/hip_bf16.h>
#include <stdint.h>

typedef unsigned short ushort_t;
typedef __attribute__((ext_vector_type(8))) short short8;
typedef __attribute__((ext_vector_type(4))) float f32x4;
typedef __attribute__((ext_vector_type(4))) int int4v;

#define N_NODES 20000
#define N_EDGES 320000
#define D 128
#define XSTRIDE 136   // padded LDS row stride (ushorts)

__device__ __forceinline__ float b2f(ushort_t u) {
    union { float f; uint32_t i; } v; v.i = ((uint32_t)u) << 16; return v.f;
}
__device__ __forceinline__ ushort_t f2b(float f) {
    union { float f; uint32_t i; } v; v.f = f;
    uint32_t r = v.i + 0x7FFFu + ((v.i >> 16) & 1u);
    return (ushort_t)(r >> 16);
}
__device__ __forceinline__ float ldf(const void* p, size_t i, bool f32) {
    return f32 ? ((const float*)p)[i] : b2f(((const ushort_t*)p)[i]);
}
__device__ __forceinline__ short8 lda8(const void* p, size_t i, bool f32) {
    if (f32) {
        const float* fp = (const float*)p + i;
        f32x4 v0 = *(const f32x4*)fp;
        f32x4 v1 = *(const f32x4*)(fp + 4);
        short8 a;
#pragma unroll
        for (int j = 0; j < 4; ++j) {
            a[j]     = (short)f2b(v0[j]);
            a[j + 4] = (short)f2b(v1[j]);
        }
        return a;
    }
    return *(const short8*)((const ushort_t*)p + i);
}
__device__ __forceinline__ float gelu_tanh(float x) {
    float u = 0.7978845608028654f * (x + 0.044715f * x * x * x);
    u = fminf(fmaxf(u, -15.f), 15.f);
    float e = __expf(2.f * u);
    float t = (e - 1.f) / (e + 1.f);
    return 0.5f * x * (1.f + t);
}
__device__ __forceinline__ int clampi(int v, int hi) {
    return v < 0 ? 0 : (v >= hi ? hi - 1 : v);
}

__device__ __forceinline__ void ln8(float x[8], const float gv[8], const float bv[8]) {
    float s1 = 0.f, s2 = 0.f;
#pragma unroll
    for (int n = 0; n < 8; ++n) { s1 += x[n]; s2 += x[n] * x[n]; }
#pragma unroll
    for (int m = 1; m < 16; m <<= 1) {
        s1 += __shfl_xor(s1, m, 64);
        s2 += __shfl_xor(s2, m, 64);
    }
    float mean = s1 * (1.f / 128.f);
    float var  = fmaxf(s2 * (1.f / 128.f) - mean * mean, 0.f);
    float rs   = rsqrtf(var + 1e-5f);
#pragma unroll
    for (int n = 0; n < 8; ++n) x[n] = (x[n] - mean) * rs * gv[n] + bv[n];
}

// f32-vs-bf16 input detection (see r3 post-mortem)
__global__ void k_detect(const uint32_t* __restrict__ raw, int* __restrict__ flag) {
    int t = blockIdx.x * blockDim.x + threadIdx.x;
    uint32_t u = raw[t];
    if (((u >> 7) & 0xFF) == 0xFF || ((u >> 23) & 0xFF) == 0xFF) atomicOr(flag, 1);
}

// ---- merged small-vector pack: 13 segments (total 4224 elems) -> bf16 arena ----
// r5 BUG: launched for 3456 threads, total is 4224 -> mlp_out_g stayed poison -> h2==0.
struct PackDesc { const void* src; int n; int dst; };
struct PackTable { PackDesc d[13]; };
#define PACK_TOTAL 4224
__global__ void k_pack_all(PackTable pt, ushort_t* __restrict__ arena,
                           const int* __restrict__ dflag) {
    const bool f32 = *dflag != 0;
    int t = blockIdx.x * blockDim.x + threadIdx.x;
    int base = 0;
#pragma unroll
    for (int s = 0; s < 13; ++s) {
        int n = pt.d[s].n;
        if (t < base + n) {
            int i = t - base;
            arena[(size_t)pt.d[s].dst * 128 + i] = f2b(ldf(pt.d[s].src, i, f32));
            return;
        }
        base += n;
    }
}

// ---- merged weight fragment transform: 6 matrices, one launch ----
struct BfragTable { const void* src[6]; int cum[7]; };
__global__ void k_bfrag_all(BfragTable bt, ushort_t* __restrict__ dst,
                            const int* __restrict__ dflag) {
    const bool f32 = *dflag != 0;
    int g = blockIdx.x * blockDim.x + threadIdx.x;
    if (g >= bt.cum[6] * 512) return;
    int kblk = g >> 9;
    int m = 0;
#pragma unroll
    for (int s = 0; s < 6; ++s) if (kblk >= bt.cum[s + 1]) m = s + 1;
    const void* src = bt.src[m];
    int kblk_l = kblk - bt.cum[m];
    int rem  = g & 511;
    int nt   = rem >> 6;
    int lane = rem & 63;
    int krow = kblk_l * 32 + ((lane >> 4) << 3);
    int col  = nt * 16 + (lane & 15);
    short8 v;
#pragma unroll
    for (int j = 0; j < 8; ++j) v[j] = (short)f2b(ldf(src, (size_t)(krow + j) * 128 + col, f32));
    *(short8*)(dst + (size_t)g * 8) = v;
}

// ---- CSR build ----
__global__ void k_count(const int* __restrict__ recv, int* __restrict__ cnt, int E) {
    int i = blockIdx.x * blockDim.x + threadIdx.x;
    if (i < E) atomicAdd(&cnt[clampi(recv[i], N_NODES)], 1);
}
__global__ void k_scan(const int* __restrict__ cnt, int* __restrict__ off, int N) {
    __shared__ int part[1024];
    const int t = threadIdx.x;
    const int chunk = (N + 1023) / 1024;
    const int base = t * chunk;
    int s = 0;
    for (int i = 0; i < chunk; ++i) if (base + i < N) s += cnt[base + i];
    part[t] = s;
    __syncthreads();
    for (int ofs = 1; ofs < 1024; ofs <<= 1) {
        int v = (t >= ofs) ? part[t - ofs] : 0;
        __syncthreads();
        part[t] += v;
        __syncthreads();
    }
    int run = (t == 0) ? 0 : part[t - 1];
    for (int i = 0; i < chunk; ++i)
        if (base + i < N) { off[base + i] = run; run += cnt[base + i]; }
    if (t == 1023) off[N] = part[1023];
}
__global__ void k_scatter(const int* __restrict__ recv, const int* __restrict__ off,
                          int* __restrict__ fill, int* __restrict__ perm, int E) {
    int i = blockIdx.x * blockDim.x + threadIdx.x;
    if (i >= E) return;
    int r = clampi(recv[i], N_NODES);
    int p = atomicAdd(&fill[r], 1);
    perm[off[r] + p] = i;
}

// ---- CSR mean-aggregation: one wave per node, lanes own 2 columns ----
__global__ __launch_bounds__(256) void k_agg_csr(
    const ushort_t* __restrict__ e, const int* __restrict__ perm,
    const int* __restrict__ off, ushort_t* __restrict__ aggb, int N)
{
    int wid  = (blockIdx.x * blockDim.x + threadIdx.x) >> 6;
    int lane = threadIdx.x & 63;
    if (wid >= N) return;
    int s = off[wid], t = off[wid + 1];
    float a0 = 0.f, a1 = 0.f;
    for (int j = s; j < t; ++j) {
        int ei = perm[j];
        uint32_t v = *(const uint32_t*)(e + (size_t)ei * 128 + lane * 2);
        a0 += b2f((ushort_t)(v & 0xFFFFu));
        a1 += b2f((ushort_t)(v >> 16));
    }
    float inv = 1.f / (float)((t - s) > 0 ? (t - s) : 1);
    uint32_t outv = (uint32_t)f2b(a0 * inv) | ((uint32_t)f2b(a1 * inv) << 16);
    *(uint32_t*)(aggb + (size_t)wid * 128 + lane * 2) = outv;
}

// ---------------- generic GEMM (embedding + mlp_out) ----------------
template<int NC, bool LN>
__global__ __launch_bounds__(256, 2) void k_gemm(
    const ushort_t* __restrict__ bfrag,
    const void* s0, int isf0, int st0, int ko0, int kl0,
    const void* s1, int isf1, int st1, int ko1, int kl1,
    const void* s2, int isf2, int st2, int ko2, int kl2,
    int rows,
    const ushort_t* __restrict__ bias,
    const ushort_t* __restrict__ gamma,
    const ushort_t* __restrict__ betap,
    ushort_t* out,
    const int* __restrict__ dflag)
{
    __shared__ __align__(16) ushort_t lds_b[128 * 128];
    const bool f32g = *dflag != 0;
    const int tid  = threadIdx.x;
    const int wave = tid >> 6, lane = tid & 63;
    const int quad = lane >> 4, l16 = lane & 15;
    const int row0 = blockIdx.x * 128 + wave * 32;

    f32x4 acc[2][8];
#pragma unroll
    for (int t = 0; t < 2; ++t)
#pragma unroll
        for (int n = 0; n < 8; ++n) acc[t][n] = (f32x4){0.f, 0.f, 0.f, 0.f};

    const ushort_t* bptr = bfrag;
#pragma unroll
    for (int c = 0; c < NC; ++c) {
        const void* src  = (c == 0) ? s0 : ((c == 1) ? s1 : s2);
        const bool  eff  = (((c == 0) ? isf0 : ((c == 1) ? isf1 : isf2)) != 0) && f32g;
        const int stride = (c == 0) ? st0 : ((c == 1) ? st1 : st2);
        const int koff   = (c == 0) ? ko0 : ((c == 1) ? ko1 : ko2);
        const int klen   = (c == 0) ? kl0 : ((c == 1) ? kl1 : kl2);

        if (c) __syncthreads();
        {
            const int4v* gs = (const int4v*)bptr;
            int4v* ld = (int4v*)lds_b;
            const int ngrp = klen * 16;
            for (int g = tid; g < ngrp; g += 256) ld[g] = gs[g];
        }
        __syncthreads();

        size_t aoff[2];
#pragma unroll
        for (int t = 0; t < 2; ++t) {
            int r  = row0 + t * 16 + l16;
            int rr = r < rows ? r : rows - 1;
            aoff[t] = (size_t)rr * stride + koff + quad * 8;
        }
        const int ksteps = klen >> 5;
        for (int ks = 0; ks < ksteps; ++ks) {
            short8 af[2];
#pragma unroll
            for (int t = 0; t < 2; ++t)
                af[t] = lda8(src, aoff[t] + ks * 32, eff);
#pragma unroll
            for (int n = 0; n < 8; ++n) {
                short8 bf = *(const short8*)(lds_b + (size_t)((ks * 8 + n) * 64 + lane) * 8);
                acc[0][n] = __builtin_amdgcn_mfma_f32_16x16x32_bf16(af[0], bf, acc[0][n], 0, 0, 0);
                acc[1][n] = __builtin_amdgcn_mfma_f32_16x16x32_bf16(af[1], bf, acc[1][n], 0, 0, 0);
            }
        }
        bptr += (size_t)klen * 128;
    }

    float bv[8], gv[8], btv[8];
#pragma unroll
    for (int n = 0; n < 8; ++n) {
        int col = n * 16 + l16;
        bv[n] = b2f(bias[col]);
        if (LN) { gv[n] = b2f(gamma[col]); btv[n] = b2f(betap[col]); }
    }
#pragma unroll
    for (int t = 0; t < 2; ++t) {
#pragma unroll
        for (int r = 0; r < 4; ++r) {
            int row = row0 + t * 16 + quad * 4 + r;
            float x[8];
#pragma unroll
            for (int n = 0; n < 8; ++n) x[n] = acc[t][n][r] + bv[n];
            if (LN) {
#pragma unroll
                for (int n = 0; n < 8; ++n) x[n] = gelu_tanh(x[n]);
                ln8(x, gv, btv);
            }
            if (row < rows) {
#pragma unroll
                for (int n = 0; n < 8; ++n)
                    out[(size_t)row * 128 + n * 16 + l16] = f2b(x[n]);
            }
        }
    }
}

// ---------------- fused edge pipeline: proj(K=384) -> MLP1 -> MLP2 + residual ----------------
__global__ __launch_bounds__(256, 2) void k_edge_fused(
    const ushort_t* __restrict__ bf_proj,
    const ushort_t* __restrict__ bf_w0,
    const ushort_t* __restrict__ bf_w1,
    ushort_t* e_glob,
    const ushort_t* __restrict__ h,
    const int* __restrict__ senders, const int* __restrict__ receivers,
    const ushort_t* __restrict__ pb,
    const ushort_t* __restrict__ b0, const ushort_t* __restrict__ g0, const ushort_t* __restrict__ be0,
    const ushort_t* __restrict__ b1, const ushort_t* __restrict__ g1, const ushort_t* __restrict__ be1)
{
    __shared__ __align__(16) ushort_t lds_b[128 * 128];
    __shared__ __align__(16) ushort_t lds_x[128 * XSTRIDE];
    const int tid  = threadIdx.x;
    const int wave = tid >> 6, lane = tid & 63;
    const int quad = lane >> 4, l16 = lane & 15;
    const int row0  = blockIdx.x * 128;   // 320000 % 128 == 0
    const int lrow0 = wave * 32;

    f32x4 acc[2][8];
#pragma unroll
    for (int t = 0; t < 2; ++t)
#pragma unroll
        for (int n = 0; n < 8; ++n) acc[t][n] = (f32x4){0.f, 0.f, 0.f, 0.f};

    for (int c = 0; c < 3; ++c) {
        if (c) __syncthreads();
        {
            const int4v* gs = (const int4v*)(bf_proj + (size_t)c * 128 * 128);
            int4v* ld = (int4v*)lds_b;
            for (int g = tid; g < 2048; g += 256) ld[g] = gs[g];
        }
        __syncthreads();
        const ushort_t* ap[2];
#pragma unroll
        for (int t = 0; t < 2; ++t) {
            int grow = row0 + lrow0 + t * 16 + l16;
            int sr = (c == 0) ? grow
                  : clampi((c == 1) ? senders[grow] : receivers[grow], N_NODES);
            const ushort_t* src = (c == 0) ? e_glob : h;
            ap[t] = src + (size_t)sr * 128 + quad * 8;
        }
        for (int ks = 0; ks < 4; ++ks) {
            short8 af[2];
#pragma unroll
            for (int t = 0; t < 2; ++t) af[t] = *(const short8*)(ap[t] + ks * 32);
#pragma unroll
            for (int n = 0; n < 8; ++n) {
                short8 bf = *(const short8*)(lds_b + (size_t)((ks * 8 + n) * 64 + lane) * 8);
                acc[0][n] = __builtin_amdgcn_mfma_f32_16x16x32_bf16(af[0], bf, acc[0][n], 0, 0, 0);
                acc[1][n] = __builtin_amdgcn_mfma_f32_16x16x32_bf16(af[1], bf, acc[1][n], 0, 0, 0);
            }
        }
    }

    {
        float bvv[8];
#pragma unroll
        for (int n = 0; n < 8; ++n) bvv[n] = b2f(pb[n * 16 + l16]);
#pragma unroll
        for (int t = 0; t < 2; ++t)
#pragma unroll
            for (int r = 0; r < 4; ++r) {
                int lrow = lrow0 + t * 16 + quad * 4 + r;
#pragma unroll
                for (int n = 0; n < 8; ++n)
                    lds_x[lrow * XSTRIDE + n * 16 + l16] = f2b(acc[t][n][r] + bvv[n]);
            }
    }
    __syncthreads();

    // MLP layer 1
    {
        const int4v* gs = (const int4v*)bf_w0;
        int4v* ld = (int4v*)lds_b;
        for (int g = tid; g < 2048; g += 256) ld[g] = gs[g];
    }
    __syncthreads();
#pragma unroll
    for (int t = 0; t < 2; ++t)
#pragma unroll
        for (int n = 0; n < 8; ++n) acc[t][n] = (f32x4){0.f, 0.f, 0.f, 0.f};
    for (int ks = 0; ks < 4; ++ks) {
        short8 af[2];
#pragma unroll
        for (int t = 0; t < 2; ++t)
            af[t] = *(const short8*)(lds_x + (lrow0 + t * 16 + l16) * XSTRIDE + ks * 32 + quad * 8);
#pragma unroll
        for (int n = 0; n < 8; ++n) {
            short8 bf = *(const short8*)(lds_b + (size_t)((ks * 8 + n) * 64 + lane) * 8);
            acc[0][n] = __builtin_amdgcn_mfma_f32_16x16x32_bf16(af[0], bf, acc[0][n], 0, 0, 0);
            acc[1][n] = __builtin_amdgcn_mfma_f32_16x16x32_bf16(af[1], bf, acc[1][n], 0, 0, 0);
        }
    }
    {
        float bv[8], gv[8], btv[8];
#pragma unroll
        for (int n = 0; n < 8; ++n) {
            int col = n * 16 + l16;
            bv[n] = b2f(b0[col]); gv[n] = b2f(g0[col]); btv[n] = b2f(be0[col]);
        }
#pragma unroll
        for (int t = 0; t < 2; ++t)
#pragma unroll
            for (int r = 0; r < 4; ++r) {
                int lrow = lrow0 + t * 16 + quad * 4 + r;
                float x[8];
#pragma unroll
                for (int n = 0; n < 8; ++n) x[n] = gelu_tanh(acc[t][n][r] + bv[n]);
                ln8(x, gv, btv);
#pragma unroll
                for (int n = 0; n < 8; ++n)
                    lds_x[lrow * XSTRIDE + n * 16 + l16] = f2b(x[n]);
            }
    }
    __syncthreads();

    // MLP layer 2 + residual writeback
    {
        const int4v* gs = (const int4v*)bf_w1;
        int4v* ld = (int4v*)lds_b;
        for (int g = tid; g < 2048; g += 256) ld[g] = gs[g];
    }
    __syncthreads();
#pragma unroll
    for (int t = 0; t < 2; ++t)
#pragma unroll
        for (int n = 0; n < 8; ++n) acc[t][n] = (f32x4){0.f, 0.f, 0.f, 0.f};
    for (int ks = 0; ks < 4; ++ks) {
        short8 af[2];
#pragma unroll
        for (int t = 0; t < 2; ++t)
            af[t] = *(const short8*)(lds_x + (lrow0 + t * 16 + l16) * XSTRIDE + ks * 32 + quad * 8);
#pragma unroll
        for (int n = 0; n < 8; ++n) {
            short8 bf = *(const short8*)(lds_b + (size_t)((ks * 8 + n) * 64 + lane) * 8);
            acc[0][n] = __builtin_amdgcn_mfma_f32_16x16x32_bf16(af[0], bf, acc[0][n], 0, 0, 0);
            acc[1][n] = __builtin_amdgcn_mfma_f32_16x16x32_bf16(af[1], bf, acc[1][n], 0, 0, 0);
        }
    }
    {
        float bv[8], gv[8], btv[8];
#pragma unroll
        for (int n = 0; n < 8; ++n) {
            int col = n * 16 + l16;
            bv[n] = b2f(b1[col]); gv[n] = b2f(g1[col]); btv[n] = b2f(be1[col]);
        }
#pragma unroll
        for (int t = 0; t < 2; ++t)
#pragma unroll
            for (int r = 0; r < 4; ++r) {
                int grow = row0 + lrow0 + t * 16 + quad * 4 + r;
                float x[8];
#pragma unroll
                for (int n = 0; n < 8; ++n) x[n] = gelu_tanh(acc[t][n][r] + bv[n]);
                ln8(x, gv, btv);
#pragma unroll
                for (int n = 0; n < 8; ++n) {
                    int col = n * 16 + l16;
                    float y = b2f(e_glob[(size_t)grow * 128 + col]) + x[n];
                    e_glob[(size_t)grow * 128 + col] = f2b(y);
                }
            }
    }
}

// ---------------- fused node pipeline: proj(K=256: h, aggb) -> MLP1 -> MLP2 + residual ----------------
__global__ __launch_bounds__(256, 2) void k_node_fused(
    const ushort_t* __restrict__ bf_proj,
    const ushort_t* __restrict__ bf_w0,
    const ushort_t* __restrict__ bf_w1,
    ushort_t* h,
    const ushort_t* __restrict__ aggb,
    const ushort_t* __restrict__ pb,
    const ushort_t* __restrict__ b0, const ushort_t* __restrict__ g0, const ushort_t* __restrict__ be0,
    const ushort_t* __restrict__ b1, const ushort_t* __restrict__ g1, const ushort_t* __restrict__ be1,
    int rows)
{
    __shared__ __align__(16) ushort_t lds_b[128 * 128];
    __shared__ __align__(16) ushort_t lds_x[128 * XSTRIDE];
    const int tid  = threadIdx.x;
    const int wave = tid >> 6, lane = tid & 63;
    const int quad = lane >> 4, l16 = lane & 15;
    const int row0  = blockIdx.x * 128;
    const int lrow0 = wave * 32;

    f32x4 acc[2][8];
#pragma unroll
    for (int t = 0; t < 2; ++t)
#pragma unroll
        for (int n = 0; n < 8; ++n) acc[t][n] = (f32x4){0.f, 0.f, 0.f, 0.f};

    for (int c = 0; c < 2; ++c) {
        if (c) __syncthreads();
        {
            const int4v* gs = (const int4v*)(bf_proj + (size_t)c * 128 * 128);
            int4v* ld = (int4v*)lds_b;
            for (int g = tid; g < 2048; g += 256) ld[g] = gs[g];
        }
        __syncthreads();
        const ushort_t* src = c ? aggb : h;
        const ushort_t* ap[2];
#pragma unroll
        for (int t = 0; t < 2; ++t) {
            int grow = row0 + lrow0 + t * 16 + l16;
            int rr = grow < rows ? grow : rows - 1;
            ap[t] = src + (size_t)rr * 128 + quad * 8;
        }
        for (int ks = 0; ks < 4; ++ks) {
            short8 af[2];
#pragma unroll
            for (int t = 0; t < 2; ++t) af[t] = *(const short8*)(ap[t] + ks * 32);
#pragma unroll
            for (int n = 0; n < 8; ++n) {
                short8 bf = *(const short8*)(lds_b + (size_t)((ks * 8 + n) * 64 + lane) * 8);
                acc[0][n] = __builtin_amdgcn_mfma_f32_16x16x32_bf16(af[0], bf, acc[0][n], 0, 0, 0);
                acc[1][n] = __builtin_amdgcn_mfma_f32_16x16x32_bf16(af[1], bf, acc[1][n], 0, 0, 0);
            }
        }
    }

    {
        float bvv[8];
#pragma unroll
        for (int n = 0; n < 8; ++n) bvv[n] = b2f(pb[n * 16 + l16]);
#pragma unroll
        for (int t = 0; t < 2; ++t)
#pragma unroll
            for (int r = 0; r < 4; ++r) {
                int lrow = lrow0 + t * 16 + quad * 4 + r;
#pragma unroll
                for (int n = 0; n < 8; ++n)
                    lds_x[lrow * XSTRIDE + n * 16 + l16] = f2b(acc[t][n][r] + bvv[n]);
            }
    }
    __syncthreads();

    // MLP1
    {
        const int4v* gs = (const int4v*)bf_w0;
        int4v* ld = (int4v*)lds_b;
        for (int g = tid; g < 2048; g += 256) ld[g] = gs[g];
    }
    __syncthreads();
#pragma unroll
    for (int t = 0; t < 2; ++t)
#pragma unroll
        for (int n = 0; n < 8; ++n) acc[t][n] = (f32x4){0.f, 0.f, 0.f, 0.f};
    for (int ks = 0; ks < 4; ++ks) {
        short8 af[2];
#pragma unroll
        for (int t = 0; t < 2; ++t)
            af[t] = *(const short8*)(lds_x + (lrow0 + t * 16 + l16) * XSTRIDE + ks * 32 + quad * 8);
#pragma unroll
        for (int n = 0; n < 8; ++n) {
            short8 bf = *(const short8*)(lds_b + (size_t)((ks * 8 + n) * 64 + lane) * 8);
            acc[0][n] = __builtin_amdgcn_mfma_f32_16x16x32_bf16(af[0], bf, acc[0][n], 0, 0, 0);
            acc[1][n] = __builtin_amdgcn_mfma_f32_16x16x32_bf16(af[1], bf, acc[1][n], 0, 0, 0);
        }
    }
    {
        float bv[8], gv[8], btv[8];
#pragma unroll
        for (int n = 0; n < 8; ++n) {
            int col = n * 16 + l16;
            bv[n] = b2f(b0[col]); gv[n] = b2f(g0[col]); btv[n] = b2f(be0[col]);
        }
#pragma unroll
        for (int t = 0; t < 2; ++t)
#pragma unroll
            for (int r = 0; r < 4; ++r) {
                int lrow = lrow0 + t * 16 + quad * 4 + r;
                float x[8];
#pragma unroll
                for (int n = 0; n < 8; ++n) x[n] = gelu_tanh(acc[t][n][r] + bv[n]);
                ln8(x, gv, btv);
#pragma unroll
                for (int n = 0; n < 8; ++n)
                    lds_x[lrow * XSTRIDE + n * 16 + l16] = f2b(x[n]);
            }
    }
    __syncthreads();

    // MLP2 + residual
    {
        const int4v* gs = (const int4v*)bf_w1;
        int4v* ld = (int4v*)lds_b;
        for (int g = tid; g < 2048; g += 256) ld[g] = gs[g];
    }
    __syncthreads();
#pragma unroll
    for (int t = 0; t < 2; ++t)
#pragma unroll
        for (int n = 0; n < 8; ++n) acc[t][n] = (f32x4){0.f, 0.f, 0.f, 0.f};
    for (int ks = 0; ks < 4; ++ks) {
        short8 af[2];
#pragma unroll
        for (int t = 0; t < 2; ++t)
            af[t] = *(const short8*)(lds_x + (lrow0 + t * 16 + l16) * XSTRIDE + ks * 32 + quad * 8);
#pragma unroll
        for (int n = 0; n < 8; ++n) {
            short8 bf = *(const short8*)(lds_b + (size_t)((ks * 8 + n) * 64 + lane) * 8);
            acc[0][n] = __builtin_amdgcn_mfma_f32_16x16x32_bf16(af[0], bf, acc[0][n], 0, 0, 0);
            acc[1][n] = __builtin_amdgcn_mfma_f32_16x16x32_bf16(af[1], bf, acc[1][n], 0, 0, 0);
        }
    }
    {
        float bv[8], gv[8], btv[8];
#pragma unroll
        for (int n = 0; n < 8; ++n) {
            int col = n * 16 + l16;
            bv[n] = b2f(b1[col]); gv[n] = b2f(g1[col]); btv[n] = b2f(be1[col]);
        }
#pragma unroll
        for (int t = 0; t < 2; ++t)
#pragma unroll
            for (int r = 0; r < 4; ++r) {
                int grow = row0 + lrow0 + t * 16 + quad * 4 + r;
                float x[8];
#pragma unroll
                for (int n = 0; n < 8; ++n) x[n] = gelu_tanh(acc[t][n][r] + bv[n]);
                ln8(x, gv, btv);
                if (grow < rows) {
#pragma unroll
                    for (int n = 0; n < 8; ++n) {
                        int col = n * 16 + l16;
                        float y = b2f(h[(size_t)grow * 128 + col]) + x[n];
                        h[(size_t)grow * 128 + col] = f2b(y);
                    }
                }
            }
    }
}

// e = edges @ w_edge_emb + b   (K=2)
__global__ void k_eedge(const void* __restrict__ edges, const void* __restrict__ w,
                        const ushort_t* __restrict__ b, ushort_t* __restrict__ e, int E,
                        const int* __restrict__ dflag) {
    const bool f32g = *dflag != 0;
    int t = blockIdx.x * blockDim.x + threadIdx.x;
    int i = t >> 4, c8 = (t & 15) << 3;
    if (i >= E) return;
    float a0 = ldf(edges, (size_t)i * 2, f32g);
    float a1 = ldf(edges, (size_t)i * 2 + 1, f32g);
    short8 v;
#pragma unroll
    for (int j = 0; j < 8; ++j) {
        int c = c8 + j;
        v[j] = (short)f2b(a0 * ldf(w, c, f32g) + a1 * ldf(w, 128 + c, f32g) + b2f(b[c]));
    }
    *(short8*)(e + (size_t)i * 128 + c8) = v;
}

// out[n][p] = h2[n] . proj_w[:,p] + proj_b[p]
__global__ void k_proj(const ushort_t* __restrict__ h2, const void* __restrict__ w,
                       const void* __restrict__ b, void* __restrict__ out, int N,
                       const int* __restrict__ dflag) {
    const bool f32g = *dflag != 0;
    int t = blockIdx.x * blockDim.x + threadIdx.x;
    int n = t / 24, p = t % 24;
    if (n >= N) return;
    float acc = ldf(b, p, f32g);
    const ushort_t* hp = h2 + (size_t)n * 128;
#pragma unroll 4
    for (int k = 0; k < 128; ++k) acc += b2f(hp[k]) * ldf(w, (size_t)k * 24 + p, f32g);
    if (f32g) ((float*)out)[(size_t)n * 24 + p] = acc;
    else      ((ushort_t*)out)[(size_t)n * 24 + p] = f2b(acc);
}

extern "C" void kernel_launch(void* const* d_in, const int* in_sizes, int n_in,
                              void* d_out, int out_size, void* d_ws, size_t ws_size,
                              hipStream_t stream) {
    const void* nodes        = d_in[0];
    const void* edges        = d_in[1];
    const int*  senders      = (const int*)d_in[2];
    const int*  receivers    = (const int*)d_in[3];
    const void* w_node_emb   = d_in[4];
    const void* b_node_emb   = d_in[5];
    const void* w_edge_emb   = d_in[6];
    const void* b_edge_emb   = d_in[7];
    const void* edge_proj_w  = d_in[8];
    const void* edge_proj_b  = d_in[9];
    const void* node_proj_w  = d_in[10];
    const void* node_proj_b  = d_in[11];
    const void* edge_mlp_w   = d_in[12];
    const void* edge_mlp_b   = d_in[13];
    const void* edge_ln_g    = d_in[14];
    const void* edge_ln_b    = d_in[15];
    const void* node_mlp_w   = d_in[16];
    const void* node_mlp_b   = d_in[17];
    const void* node_ln_g    = d_in[18];
    const void* node_ln_b    = d_in[19];
    const void* mlp_out_w    = d_in[20];
    const void* mlp_out_b    = d_in[21];
    const void* mlp_out_g    = d_in[22];
    const void* mlp_out_beta = d_in[23];
    const void* proj_w       = d_in[24];
    const void* proj_b       = d_in[25];

    // workspace layout (~90 MiB)
    char* ws = (char*)d_ws;
    ushort_t* bf_arena = (ushort_t*)ws;     ws += (size_t)85 * 512 * 8 * 2;   // 85 kblks
    ushort_t* h    = (ushort_t*)ws;         ws += (size_t)N_NODES * D * 2;
    ushort_t* e    = (ushort_t*)ws;         ws += (size_t)N_EDGES * D * 2;
    ushort_t* aggb = (ushort_t*)ws;         ws += (size_t)N_NODES * D * 2;
    int*      cnti = (int*)ws;              ws += (size_t)N_NODES * 4;
    int*      fill = (int*)ws;              ws += (size_t)N_NODES * 4;
    int*      offs = (int*)ws;              ws += (size_t)(N_NODES + 1) * 4;
    int*      perm = (int*)ws;              ws += (size_t)N_EDGES * 4;
    int*      flag = (int*)ws;              ws += 256;
    ushort_t* bvec = (ushort_t*)ws;         ws += (size_t)34 * 128 * 2;
    ushort_t* h2   = aggb;                  // alias: aggb dead after last node layer

    // bfrag arena sub-offsets (kblk units): nodeemb 0..9, edgeproj 9..33,
    // nodeproj 33..49, edgemlp 49..65, nodemlp 65..81, mlpout 81..85
    ushort_t* bf_nodeemb  = bf_arena + (size_t)0  * 4096;
    ushort_t* bf_edgeproj = bf_arena + (size_t)9  * 4096;
    ushort_t* bf_nodeproj = bf_arena + (size_t)33 * 4096;
    ushort_t* bf_edgemlp  = bf_arena + (size_t)49 * 4096;
    ushort_t* bf_nodemlp  = bf_arena + (size_t)65 * 4096;
    ushort_t* bf_mlpout   = bf_arena + (size_t)81 * 4096;

    hipMemsetAsync(flag, 0, 256, stream);
    k_detect<<<256, 256, 0, stream>>>((const uint32_t*)nodes, flag);

    // one launch: pack all 1-D params into bf16 arena (total = 4224 elements)
    PackTable pt = {{
        { b_node_emb,   128, 0  }, { b_edge_emb,   128, 1  },
        { edge_proj_b,  256, 2  }, { node_proj_b,  256, 4  },
        { edge_mlp_b,   512, 6  }, { edge_ln_g,    512, 10 }, { edge_ln_b, 512, 14 },
        { node_mlp_b,   512, 18 }, { node_ln_g,    512, 22 }, { node_ln_b, 512, 26 },
        { mlp_out_b,    128, 30 }, { mlp_out_g,    128, 31 }, { mlp_out_beta, 128, 32 },
    }};
    k_pack_all<<<(PACK_TOTAL + 255) / 256, 256, 0, stream>>>(pt, bvec, flag);

    // one launch: all weight fragment transforms
    BfragTable bt;
    bt.src[0] = w_node_emb;  bt.src[1] = edge_proj_w; bt.src[2] = node_proj_w;
    bt.src[3] = edge_mlp_w;  bt.src[4] = node_mlp_w;  bt.src[5] = mlp_out_w;
    bt.cum[0] = 0; bt.cum[1] = 9; bt.cum[2] = 33; bt.cum[3] = 49;
    bt.cum[4] = 65; bt.cum[5] = 81; bt.cum[6] = 85;
    k_bfrag_all<<<(85 * 512 + 255) / 256, 256, 0, stream>>>(bt, bf_arena, flag);

    // CSR build (cnti & fill contiguous -> one memset)
    hipMemsetAsync(cnti, 0, (size_t)N_NODES * 8, stream);
    k_count<<<(N_EDGES + 255) / 256, 256, 0, stream>>>(receivers, cnti, N_EDGES);
    k_scan<<<1, 1024, 0, stream>>>(cnti, offs, N_NODES);
    k_scatter<<<(N_EDGES + 255) / 256, 256, 0, stream>>>(receivers, offs, fill, perm, N_EDGES);

    k_eedge<<<(N_EDGES * 16) / 256, 256, 0, stream>>>(edges, w_edge_emb, bvec + 128, e, N_EDGES, flag);
    {
        const int grid = (N_NODES + 127) / 128;
        k_gemm<3, false><<<grid, 256, 0, stream>>>(
            bf_nodeemb,
            nodes, 1, 288, 0,   128,
            nodes, 1, 288, 128, 128,
            nodes, 1, 288, 256, 32,
            N_NODES, bvec + 0 * 128, nullptr, nullptr, h, flag);
    }

    const int gridE = N_EDGES / 128;           // 2500
    const int gridN = (N_NODES + 127) / 128;   // 157
    const int gridA = (N_NODES * 64 + 255) / 256;

    for (int l = 0; l < 2; ++l) {
        k_edge_fused<<<gridE, 256, 0, stream>>>(
            bf_edgeproj + (size_t)l * 12 * 4096,
            bf_edgemlp + (size_t)(l * 2 + 0) * 4 * 4096,
            bf_edgemlp + (size_t)(l * 2 + 1) * 4 * 4096,
            e, h, senders, receivers,
            bvec + (size_t)(2 + l) * 128,
            bvec + (size_t)(6  + l * 2) * 128,     bvec + (size_t)(10 + l * 2) * 128,     bvec + (size_t)(14 + l * 2) * 128,
            bvec + (size_t)(6  + l * 2 + 1) * 128, bvec + (size_t)(10 + l * 2 + 1) * 128, bvec + (size_t)(14 + l * 2 + 1) * 128);
        k_agg_csr<<<gridA, 256, 0, stream>>>(e, perm, offs, aggb, N_NODES);
        k_node_fused<<<gridN, 256, 0, stream>>>(
            bf_nodeproj + (size_t)l * 8 * 4096,
            bf_nodemlp + (size_t)(l * 2 + 0) * 4 * 4096,
            bf_nodemlp + (size_t)(l * 2 + 1) * 4 * 4096,
            h, aggb,
            bvec + (size_t)(4 + l) * 128,
            bvec + (size_t)(18 + l * 2) * 128,     bvec + (size_t)(22 + l * 2) * 128,     bvec + (size_t)(26 + l * 2) * 128,
            bvec + (size_t)(18 + l * 2 + 1) * 128, bvec + (size_t)(22 + l * 2 + 1) * 128, bvec + (size_t)(26 + l * 2 + 1) * 128,
            N_NODES);
    }

    k_gemm<1, true><<<gridN, 256, 0, stream>>>(
        bf_mlpout,
        h, 0, 128, 0, 128,
        nullptr, 0, 0, 0, 0,
        nullptr, 0, 0, 0, 0,
        N_NODES, bvec + 30 * 128, bvec + 31 * 128, bvec + 32 * 128, h2, flag);
    k_proj<<<(N_NODES * 24 + 255) / 256, 256, 0, stream>>>(h2, proj_w, proj_b, d_out, N_NODES, flag);
}